// Round 1
// baseline (534.647 us; speedup 1.0000x reference)
//
#include <hip/hip_runtime.h>

// GCNEncoder: h1 = relu(SpMM(x@W0) + b0); h2 = relu(SpMM(h1@W1) + b1)
// mean = relu(h2@Wm1+bm1)@Wm2+bm2 ; logvar = relu(h2@Wv1+bv1)@Wv2+bv2
// All fp32. SpMM via on-device CSR build (no fp32 atomics in hot loop).

// ---------------------------------------------------------------- GEMM
// C[n,M] = A[n,K] @ W[K,M] (+bias, relu). 256 thr, 4x4 register blocking,
// K chunked by 64 so LDS stays <64KB/block.
template<int K, int M, bool RELU, bool BIAS>
__global__ __launch_bounds__(256)
void gemm_kernel(const float* __restrict__ A, const float* __restrict__ W,
                 const float* __restrict__ bias, float* __restrict__ C, int n) {
  constexpr int CG = M / 4;        // col groups (32 for M=128, 16 for M=64)
  constexpr int RG = 256 / CG;     // row groups
  constexpr int ROWS = RG * 4;     // rows per block (32 or 64)
  constexpr int KC = 64;           // K chunk
  constexpr int PAD = (CG == 32) ? 0 : 4;  // pad keeps a-reads <=2-way (free)

  __shared__ float As[ROWS][KC + PAD];
  __shared__ float Ws[KC][M];

  const int t = threadIdx.x;
  const int row0 = blockIdx.x * ROWS;
  const int cg = t % CG, rg = t / CG;
  const int c0 = cg * 4, r0 = rg * 4;

  float acc[4][4] = {};

  for (int kc = 0; kc < K; kc += KC) {
    // stage W chunk [KC x M]
    for (int i = t; i < KC * M / 4; i += 256) {
      int lr = i / (M / 4), lc = (i % (M / 4)) * 4;
      *(float4*)&Ws[lr][lc] = *(const float4*)&W[(size_t)(kc + lr) * M + lc];
    }
    // stage A chunk [ROWS x KC]
    for (int i = t; i < ROWS * KC / 4; i += 256) {
      int lr = i / (KC / 4), lc = (i % (KC / 4)) * 4;
      float4 v = make_float4(0.f, 0.f, 0.f, 0.f);
      int gr = row0 + lr;
      if (gr < n) v = *(const float4*)&A[(size_t)gr * K + kc + lc];
      *(float4*)&As[lr][lc] = v;
    }
    __syncthreads();

#pragma unroll 4
    for (int k4 = 0; k4 < KC; k4 += 4) {
      float4 av[4];
#pragma unroll
      for (int i = 0; i < 4; ++i) av[i] = *(const float4*)&As[r0 + i][k4];
#pragma unroll
      for (int j = 0; j < 4; ++j) {
        float4 b = *(const float4*)&Ws[k4 + j][c0];
#pragma unroll
        for (int i = 0; i < 4; ++i) {
          float a = (j == 0) ? av[i].x : (j == 1) ? av[i].y : (j == 2) ? av[i].z : av[i].w;
          acc[i][0] = fmaf(a, b.x, acc[i][0]);
          acc[i][1] = fmaf(a, b.y, acc[i][1]);
          acc[i][2] = fmaf(a, b.z, acc[i][2]);
          acc[i][3] = fmaf(a, b.w, acc[i][3]);
        }
      }
    }
    __syncthreads();
  }

#pragma unroll
  for (int i = 0; i < 4; ++i) {
    int r = row0 + r0 + i;
    if (r < n) {
      float4 v = make_float4(acc[i][0], acc[i][1], acc[i][2], acc[i][3]);
      if constexpr (BIAS) {
        v.x += bias[c0 + 0]; v.y += bias[c0 + 1];
        v.z += bias[c0 + 2]; v.w += bias[c0 + 3];
      }
      if constexpr (RELU) {
        v.x = fmaxf(v.x, 0.f); v.y = fmaxf(v.y, 0.f);
        v.z = fmaxf(v.z, 0.f); v.w = fmaxf(v.w, 0.f);
      }
      *(float4*)&C[(size_t)r * M + c0] = v;
    }
  }
}

// ---------------------------------------------------------------- CSR build
__global__ void hist_kernel(const int* __restrict__ rows, int* __restrict__ counts, int e) {
  int i = blockIdx.x * blockDim.x + threadIdx.x;
  if (i < e) atomicAdd(&counts[rows[i]], 1);
}

// single-block exclusive scan: row_ptr[0]=0, row_ptr[i+1]=sum(counts[0..i])
__global__ __launch_bounds__(1024)
void scan_kernel(const int* __restrict__ counts, int* __restrict__ row_ptr, int n) {
  __shared__ int sdata[1024];
  __shared__ int s_carry;
  int t = threadIdx.x;
  if (t == 0) { s_carry = 0; row_ptr[0] = 0; }
  __syncthreads();
  for (int base = 0; base < n; base += 1024) {
    int i = base + t;
    sdata[t] = (i < n) ? counts[i] : 0;
    __syncthreads();
    for (int off = 1; off < 1024; off <<= 1) {
      int add = (t >= off) ? sdata[t - off] : 0;
      __syncthreads();
      sdata[t] += add;
      __syncthreads();
    }
    int carry = s_carry;
    __syncthreads();
    if (i < n) row_ptr[i + 1] = sdata[t] + carry;
    if (t == 1023) s_carry = carry + sdata[1023];
    __syncthreads();
  }
}

__global__ void scatter_kernel(const int* __restrict__ rows, const int* __restrict__ cols,
                               const float* __restrict__ vals, const int* __restrict__ row_ptr,
                               int* __restrict__ cursor, int* __restrict__ s_col,
                               float* __restrict__ s_val, int e) {
  int i = blockIdx.x * blockDim.x + threadIdx.x;
  if (i < e) {
    int r = rows[i];
    int p = row_ptr[r] + atomicAdd(&cursor[r], 1);
    s_col[p] = cols[i];
    s_val[p] = vals[i];
  }
}

// ---------------------------------------------------------------- SpMM (CSR gather)
// out[r,:] = relu( sum_e val_e * sup[col_e,:] + bias )  — one block per row,
// 128 threads = 128 feature dims, coalesced 512B row reads.
__global__ __launch_bounds__(128)
void spmm_kernel(const float* __restrict__ sup, const int* __restrict__ row_ptr,
                 const int* __restrict__ s_col, const float* __restrict__ s_val,
                 const float* __restrict__ bias, float* __restrict__ out, int n) {
  int r = blockIdx.x;
  if (r >= n) return;
  int d = threadIdx.x;
  int beg = row_ptr[r], end = row_ptr[r + 1];
  float acc = 0.f;
  int i = beg;
  for (; i + 1 < end; i += 2) {
    int c0 = s_col[i], c1 = s_col[i + 1];
    float v0 = s_val[i], v1 = s_val[i + 1];
    acc = fmaf(v0, sup[(size_t)c0 * 128 + d], acc);
    acc = fmaf(v1, sup[(size_t)c1 * 128 + d], acc);
  }
  if (i < end) acc = fmaf(s_val[i], sup[(size_t)s_col[i] * 128 + d], acc);
  out[(size_t)r * 128 + d] = fmaxf(acc + bias[d], 0.f);
}

// ---------------------------------------------------------------- launch
extern "C" void kernel_launch(void* const* d_in, const int* in_sizes, int n_in,
                              void* d_out, int out_size, void* d_ws, size_t ws_size,
                              hipStream_t stream) {
  const float* x        = (const float*)d_in[0];
  const int*   edge_row = (const int*)d_in[1];
  const int*   edge_col = (const int*)d_in[2];
  const float* edge_val = (const float*)d_in[3];
  const float* W_gc0 = (const float*)d_in[4];
  const float* b_gc0 = (const float*)d_in[5];
  const float* W_gc1 = (const float*)d_in[6];
  const float* b_gc1 = (const float*)d_in[7];
  const float* Wm1 = (const float*)d_in[8];
  const float* bm1 = (const float*)d_in[9];
  const float* Wm2 = (const float*)d_in[10];
  const float* bm2 = (const float*)d_in[11];
  const float* Wv1 = (const float*)d_in[12];
  const float* bv1 = (const float*)d_in[13];
  const float* Wv2 = (const float*)d_in[14];
  const float* bv2 = (const float*)d_in[15];

  const int N = in_sizes[0] / 128;   // 50000
  const int E = in_sizes[1];         // 800000

  // workspace layout (bytes) — ~58.2 MB total
  char* ws = (char*)d_ws;
  float* bufA   = (float*)(ws);                              // N*128 f32 (support; later head-hidden)
  float* bufB   = (float*)(ws + (size_t)N * 128 * 4);        // N*128 f32 (h1 / h2)
  float* s_val  = (float*)(ws + (size_t)N * 128 * 8);        // E f32
  int*   s_col  = (int*)  (ws + (size_t)N * 128 * 8 + (size_t)E * 4);
  int*   row_ptr= (int*)  (ws + (size_t)N * 128 * 8 + (size_t)E * 8);
  // pad row_ptr region to 200,064 B
  int*   counts = (int*)  ((char*)row_ptr + 200064);
  int*   cursor = counts + N;
  float* t1     = bufA;                                      // N*64 f32, reuses bufA

  float* out_mean = (float*)d_out;
  float* out_lvar = out_mean + (size_t)N * 64;

  // ---- CSR build (same work every call; ws re-poisoned each launch)
  hipMemsetAsync(counts, 0, (size_t)2 * N * 4, stream);
  hist_kernel<<<(E + 255) / 256, 256, 0, stream>>>(edge_row, counts, E);
  scan_kernel<<<1, 1024, 0, stream>>>(counts, row_ptr, N);
  scatter_kernel<<<(E + 255) / 256, 256, 0, stream>>>(edge_row, edge_col, edge_val,
                                                      row_ptr, cursor, s_col, s_val, E);

  // ---- layer 1: support = x @ W_gc0 ; h1 = relu(agg + b_gc0)
  gemm_kernel<128, 128, false, false><<<(N + 31) / 32, 256, 0, stream>>>(x, W_gc0, nullptr, bufA, N);
  spmm_kernel<<<N, 128, 0, stream>>>(bufA, row_ptr, s_col, s_val, b_gc0, bufB, N);

  // ---- layer 2
  gemm_kernel<128, 128, false, false><<<(N + 31) / 32, 256, 0, stream>>>(bufB, W_gc1, nullptr, bufA, N);
  spmm_kernel<<<N, 128, 0, stream>>>(bufA, row_ptr, s_col, s_val, b_gc1, bufB, N);
  // bufB now holds h2

  // ---- mean head
  gemm_kernel<128, 64, true, true><<<(N + 63) / 64, 256, 0, stream>>>(bufB, Wm1, bm1, t1, N);
  gemm_kernel<64, 64, false, true><<<(N + 63) / 64, 256, 0, stream>>>(t1, Wm2, bm2, out_mean, N);

  // ---- logvar head
  gemm_kernel<128, 64, true, true><<<(N + 63) / 64, 256, 0, stream>>>(bufB, Wv1, bv1, t1, N);
  gemm_kernel<64, 64, false, true><<<(N + 63) / 64, 256, 0, stream>>>(t1, Wv2, bv2, out_lvar, N);
}

// Round 2
// 452.359 us; speedup vs baseline: 1.1819x; 1.1819x over previous
//
#include <hip/hip_runtime.h>

// GCNEncoder: h1 = relu(SpMM(x@W0) + b0); h2 = relu(SpMM(h1@W1) + b1)
// mean = relu(h2@Wm1+bm1)@Wm2+bm2 ; logvar = relu(h2@Wv1+bv1)@Wv2+bv2
// All fp32. SpMM via on-device CSR build (no fp32 atomics in hot loop).
// R2: replaced 90µs single-block scan with 3-kernel hierarchical scan.

// ---------------------------------------------------------------- GEMM
// C[n,M] = A[n,K] @ W[K,M] (+bias, relu). 256 thr, 4x4 register blocking,
// K chunked by 64 so LDS stays <64KB/block.
template<int K, int M, bool RELU, bool BIAS>
__global__ __launch_bounds__(256)
void gemm_kernel(const float* __restrict__ A, const float* __restrict__ W,
                 const float* __restrict__ bias, float* __restrict__ C, int n) {
  constexpr int CG = M / 4;        // col groups (32 for M=128, 16 for M=64)
  constexpr int RG = 256 / CG;     // row groups
  constexpr int ROWS = RG * 4;     // rows per block (32 or 64)
  constexpr int KC = 64;           // K chunk
  constexpr int PAD = (CG == 32) ? 0 : 4;  // pad keeps a-reads <=2-way (free)

  __shared__ float As[ROWS][KC + PAD];
  __shared__ float Ws[KC][M];

  const int t = threadIdx.x;
  const int row0 = blockIdx.x * ROWS;
  const int cg = t % CG, rg = t / CG;
  const int c0 = cg * 4, r0 = rg * 4;

  float acc[4][4] = {};

  for (int kc = 0; kc < K; kc += KC) {
    // stage W chunk [KC x M]
    for (int i = t; i < KC * M / 4; i += 256) {
      int lr = i / (M / 4), lc = (i % (M / 4)) * 4;
      *(float4*)&Ws[lr][lc] = *(const float4*)&W[(size_t)(kc + lr) * M + lc];
    }
    // stage A chunk [ROWS x KC]
    for (int i = t; i < ROWS * KC / 4; i += 256) {
      int lr = i / (KC / 4), lc = (i % (KC / 4)) * 4;
      float4 v = make_float4(0.f, 0.f, 0.f, 0.f);
      int gr = row0 + lr;
      if (gr < n) v = *(const float4*)&A[(size_t)gr * K + kc + lc];
      *(float4*)&As[lr][lc] = v;
    }
    __syncthreads();

#pragma unroll 4
    for (int k4 = 0; k4 < KC; k4 += 4) {
      float4 av[4];
#pragma unroll
      for (int i = 0; i < 4; ++i) av[i] = *(const float4*)&As[r0 + i][k4];
#pragma unroll
      for (int j = 0; j < 4; ++j) {
        float4 b = *(const float4*)&Ws[k4 + j][c0];
#pragma unroll
        for (int i = 0; i < 4; ++i) {
          float a = (j == 0) ? av[i].x : (j == 1) ? av[i].y : (j == 2) ? av[i].z : av[i].w;
          acc[i][0] = fmaf(a, b.x, acc[i][0]);
          acc[i][1] = fmaf(a, b.y, acc[i][1]);
          acc[i][2] = fmaf(a, b.z, acc[i][2]);
          acc[i][3] = fmaf(a, b.w, acc[i][3]);
        }
      }
    }
    __syncthreads();
  }

#pragma unroll
  for (int i = 0; i < 4; ++i) {
    int r = row0 + r0 + i;
    if (r < n) {
      float4 v = make_float4(acc[i][0], acc[i][1], acc[i][2], acc[i][3]);
      if constexpr (BIAS) {
        v.x += bias[c0 + 0]; v.y += bias[c0 + 1];
        v.z += bias[c0 + 2]; v.w += bias[c0 + 3];
      }
      if constexpr (RELU) {
        v.x = fmaxf(v.x, 0.f); v.y = fmaxf(v.y, 0.f);
        v.z = fmaxf(v.z, 0.f); v.w = fmaxf(v.w, 0.f);
      }
      *(float4*)&C[(size_t)r * M + c0] = v;
    }
  }
}

// ---------------------------------------------------------------- CSR build
__global__ void hist_kernel(const int* __restrict__ rows, int* __restrict__ counts, int e) {
  int i = blockIdx.x * blockDim.x + threadIdx.x;
  if (i < e) atomicAdd(&counts[rows[i]], 1);
}

// hierarchical scan, step 1: per-block inclusive scan of counts -> tmp,
// block total -> bsum[block]
__global__ __launch_bounds__(256)
void scan1_kernel(const int* __restrict__ counts, int* __restrict__ tmp,
                  int* __restrict__ bsum, int n) {
  __shared__ int sdata[256];
  int t = threadIdx.x;
  int i = blockIdx.x * 256 + t;
  sdata[t] = (i < n) ? counts[i] : 0;
  __syncthreads();
#pragma unroll
  for (int off = 1; off < 256; off <<= 1) {
    int add = (t >= off) ? sdata[t - off] : 0;
    __syncthreads();
    sdata[t] += add;
    __syncthreads();
  }
  if (i < n) tmp[i] = sdata[t];
  if (t == 255) bsum[blockIdx.x] = sdata[255];
}

// step 2: exclusive scan of block sums (nb <= 256) in one block
__global__ __launch_bounds__(256)
void scan2_kernel(const int* __restrict__ bsum, int* __restrict__ boff, int nb) {
  __shared__ int sdata[256];
  int t = threadIdx.x;
  sdata[t] = (t < nb) ? bsum[t] : 0;
  __syncthreads();
#pragma unroll
  for (int off = 1; off < 256; off <<= 1) {
    int add = (t >= off) ? sdata[t - off] : 0;
    __syncthreads();
    sdata[t] += add;
    __syncthreads();
  }
  if (t < nb) boff[t] = (t == 0) ? 0 : sdata[t - 1];
}

// step 3: row_ptr[i+1] = tmp[i] + boff[i/256]; row_ptr[0] = 0
__global__ __launch_bounds__(256)
void scan3_kernel(const int* __restrict__ tmp, const int* __restrict__ boff,
                  int* __restrict__ row_ptr, int n) {
  int i = blockIdx.x * 256 + threadIdx.x;
  if (i == 0) row_ptr[0] = 0;
  if (i < n) row_ptr[i + 1] = tmp[i] + boff[i >> 8];
}

__global__ void scatter_kernel(const int* __restrict__ rows, const int* __restrict__ cols,
                               const float* __restrict__ vals, const int* __restrict__ row_ptr,
                               int* __restrict__ cursor, int* __restrict__ s_col,
                               float* __restrict__ s_val, int e) {
  int i = blockIdx.x * blockDim.x + threadIdx.x;
  if (i < e) {
    int r = rows[i];
    int p = row_ptr[r] + atomicAdd(&cursor[r], 1);
    s_col[p] = cols[i];
    s_val[p] = vals[i];
  }
}

// ---------------------------------------------------------------- SpMM (CSR gather)
// out[r,:] = relu( sum_e val_e * sup[col_e,:] + bias )  — one block per row,
// 128 threads = 128 feature dims, coalesced 512B row reads.
__global__ __launch_bounds__(128)
void spmm_kernel(const float* __restrict__ sup, const int* __restrict__ row_ptr,
                 const int* __restrict__ s_col, const float* __restrict__ s_val,
                 const float* __restrict__ bias, float* __restrict__ out, int n) {
  int r = blockIdx.x;
  if (r >= n) return;
  int d = threadIdx.x;
  int beg = row_ptr[r], end = row_ptr[r + 1];
  float acc = 0.f;
  int i = beg;
  for (; i + 1 < end; i += 2) {
    int c0 = s_col[i], c1 = s_col[i + 1];
    float v0 = s_val[i], v1 = s_val[i + 1];
    acc = fmaf(v0, sup[(size_t)c0 * 128 + d], acc);
    acc = fmaf(v1, sup[(size_t)c1 * 128 + d], acc);
  }
  if (i < end) acc = fmaf(s_val[i], sup[(size_t)s_col[i] * 128 + d], acc);
  out[(size_t)r * 128 + d] = fmaxf(acc + bias[d], 0.f);
}

// ---------------------------------------------------------------- launch
extern "C" void kernel_launch(void* const* d_in, const int* in_sizes, int n_in,
                              void* d_out, int out_size, void* d_ws, size_t ws_size,
                              hipStream_t stream) {
  const float* x        = (const float*)d_in[0];
  const int*   edge_row = (const int*)d_in[1];
  const int*   edge_col = (const int*)d_in[2];
  const float* edge_val = (const float*)d_in[3];
  const float* W_gc0 = (const float*)d_in[4];
  const float* b_gc0 = (const float*)d_in[5];
  const float* W_gc1 = (const float*)d_in[6];
  const float* b_gc1 = (const float*)d_in[7];
  const float* Wm1 = (const float*)d_in[8];
  const float* bm1 = (const float*)d_in[9];
  const float* Wm2 = (const float*)d_in[10];
  const float* bm2 = (const float*)d_in[11];
  const float* Wv1 = (const float*)d_in[12];
  const float* bv1 = (const float*)d_in[13];
  const float* Wv2 = (const float*)d_in[14];
  const float* bv2 = (const float*)d_in[15];

  const int N = in_sizes[0] / 128;   // 50000
  const int E = in_sizes[1];         // 800000
  const int NB = (N + 255) / 256;    // scan blocks (196)

  // workspace layout (bytes)
  char* ws = (char*)d_ws;
  float* bufA   = (float*)(ws);                              // N*128 f32
  float* bufB   = (float*)(ws + (size_t)N * 128 * 4);        // N*128 f32
  float* s_val  = (float*)(ws + (size_t)N * 128 * 8);        // E f32
  int*   s_col  = (int*)  (ws + (size_t)N * 128 * 8 + (size_t)E * 4);
  int*   row_ptr= (int*)  (ws + (size_t)N * 128 * 8 + (size_t)E * 8);
  int*   counts = (int*)  ((char*)row_ptr + 200064);         // N ints
  int*   cursor = counts + N;                                // N ints
  int*   tmp    = cursor + N;                                // N ints
  int*   bsum   = tmp + N;                                   // 256 ints
  int*   boff   = bsum + 256;                                // 256 ints
  float* t1     = bufA;                                      // N*64 f32, reuses bufA

  float* out_mean = (float*)d_out;
  float* out_lvar = out_mean + (size_t)N * 64;

  // ---- CSR build (same work every call; ws re-poisoned each launch)
  hipMemsetAsync(counts, 0, (size_t)2 * N * 4, stream);
  hist_kernel<<<(E + 255) / 256, 256, 0, stream>>>(edge_row, counts, E);
  scan1_kernel<<<NB, 256, 0, stream>>>(counts, tmp, bsum, N);
  scan2_kernel<<<1, 256, 0, stream>>>(bsum, boff, NB);
  scan3_kernel<<<NB, 256, 0, stream>>>(tmp, boff, row_ptr, N);
  scatter_kernel<<<(E + 255) / 256, 256, 0, stream>>>(edge_row, edge_col, edge_val,
                                                      row_ptr, cursor, s_col, s_val, E);

  // ---- layer 1: support = x @ W_gc0 ; h1 = relu(agg + b_gc0)
  gemm_kernel<128, 128, false, false><<<(N + 31) / 32, 256, 0, stream>>>(x, W_gc0, nullptr, bufA, N);
  spmm_kernel<<<N, 128, 0, stream>>>(bufA, row_ptr, s_col, s_val, b_gc0, bufB, N);

  // ---- layer 2
  gemm_kernel<128, 128, false, false><<<(N + 31) / 32, 256, 0, stream>>>(bufB, W_gc1, nullptr, bufA, N);
  spmm_kernel<<<N, 128, 0, stream>>>(bufA, row_ptr, s_col, s_val, b_gc1, bufB, N);
  // bufB now holds h2

  // ---- mean head
  gemm_kernel<128, 64, true, true><<<(N + 63) / 64, 256, 0, stream>>>(bufB, Wm1, bm1, t1, N);
  gemm_kernel<64, 64, false, true><<<(N + 63) / 64, 256, 0, stream>>>(t1, Wm2, bm2, out_mean, N);

  // ---- logvar head
  gemm_kernel<128, 64, true, true><<<(N + 63) / 64, 256, 0, stream>>>(bufB, Wv1, bv1, t1, N);
  gemm_kernel<64, 64, false, true><<<(N + 63) / 64, 256, 0, stream>>>(t1, Wv2, bv2, out_lvar, N);
}

// Round 3
// 436.951 us; speedup vs baseline: 1.2236x; 1.0353x over previous
//
#include <hip/hip_runtime.h>

// GCNEncoder: h1 = relu(SpMM(x@W0) + b0); h2 = relu(SpMM(h1@W1) + b1)
// mean = relu(h2@Wm1+bm1)@Wm2+bm2 ; logvar = relu(h2@Wv1+bv1)@Wv2+bv2
// All fp32. SpMM via on-device CSR build (no fp32 atomics in hot loop).
// R2: hierarchical scan (90us -> ~5us).
// R3: SpMM restructured for memory-level parallelism: float4 gathers,
//     32 lanes per row, unroll 4 -> 4 outstanding 512B row-gathers per row
//     (was 2x 4B per lane). Latency-bound -> more bytes in flight.

// ---------------------------------------------------------------- GEMM
// C[n,M] = A[n,K] @ W[K,M] (+bias, relu). 256 thr, 4x4 register blocking,
// K chunked by 64 so LDS stays <64KB/block.
template<int K, int M, bool RELU, bool BIAS>
__global__ __launch_bounds__(256)
void gemm_kernel(const float* __restrict__ A, const float* __restrict__ W,
                 const float* __restrict__ bias, float* __restrict__ C, int n) {
  constexpr int CG = M / 4;        // col groups (32 for M=128, 16 for M=64)
  constexpr int RG = 256 / CG;     // row groups
  constexpr int ROWS = RG * 4;     // rows per block (32 or 64)
  constexpr int KC = 64;           // K chunk
  constexpr int PAD = (CG == 32) ? 0 : 4;  // pad keeps a-reads <=2-way (free)

  __shared__ float As[ROWS][KC + PAD];
  __shared__ float Ws[KC][M];

  const int t = threadIdx.x;
  const int row0 = blockIdx.x * ROWS;
  const int cg = t % CG, rg = t / CG;
  const int c0 = cg * 4, r0 = rg * 4;

  float acc[4][4] = {};

  for (int kc = 0; kc < K; kc += KC) {
    // stage W chunk [KC x M]
    for (int i = t; i < KC * M / 4; i += 256) {
      int lr = i / (M / 4), lc = (i % (M / 4)) * 4;
      *(float4*)&Ws[lr][lc] = *(const float4*)&W[(size_t)(kc + lr) * M + lc];
    }
    // stage A chunk [ROWS x KC]
    for (int i = t; i < ROWS * KC / 4; i += 256) {
      int lr = i / (KC / 4), lc = (i % (KC / 4)) * 4;
      float4 v = make_float4(0.f, 0.f, 0.f, 0.f);
      int gr = row0 + lr;
      if (gr < n) v = *(const float4*)&A[(size_t)gr * K + kc + lc];
      *(float4*)&As[lr][lc] = v;
    }
    __syncthreads();

#pragma unroll 4
    for (int k4 = 0; k4 < KC; k4 += 4) {
      float4 av[4];
#pragma unroll
      for (int i = 0; i < 4; ++i) av[i] = *(const float4*)&As[r0 + i][k4];
#pragma unroll
      for (int j = 0; j < 4; ++j) {
        float4 b = *(const float4*)&Ws[k4 + j][c0];
#pragma unroll
        for (int i = 0; i < 4; ++i) {
          float a = (j == 0) ? av[i].x : (j == 1) ? av[i].y : (j == 2) ? av[i].z : av[i].w;
          acc[i][0] = fmaf(a, b.x, acc[i][0]);
          acc[i][1] = fmaf(a, b.y, acc[i][1]);
          acc[i][2] = fmaf(a, b.z, acc[i][2]);
          acc[i][3] = fmaf(a, b.w, acc[i][3]);
        }
      }
    }
    __syncthreads();
  }

#pragma unroll
  for (int i = 0; i < 4; ++i) {
    int r = row0 + r0 + i;
    if (r < n) {
      float4 v = make_float4(acc[i][0], acc[i][1], acc[i][2], acc[i][3]);
      if constexpr (BIAS) {
        v.x += bias[c0 + 0]; v.y += bias[c0 + 1];
        v.z += bias[c0 + 2]; v.w += bias[c0 + 3];
      }
      if constexpr (RELU) {
        v.x = fmaxf(v.x, 0.f); v.y = fmaxf(v.y, 0.f);
        v.z = fmaxf(v.z, 0.f); v.w = fmaxf(v.w, 0.f);
      }
      *(float4*)&C[(size_t)r * M + c0] = v;
    }
  }
}

// ---------------------------------------------------------------- CSR build
__global__ void hist_kernel(const int* __restrict__ rows, int* __restrict__ counts, int e) {
  int i = blockIdx.x * blockDim.x + threadIdx.x;
  if (i < e) atomicAdd(&counts[rows[i]], 1);
}

// hierarchical scan, step 1: per-block inclusive scan of counts -> tmp,
// block total -> bsum[block]
__global__ __launch_bounds__(256)
void scan1_kernel(const int* __restrict__ counts, int* __restrict__ tmp,
                  int* __restrict__ bsum, int n) {
  __shared__ int sdata[256];
  int t = threadIdx.x;
  int i = blockIdx.x * 256 + t;
  sdata[t] = (i < n) ? counts[i] : 0;
  __syncthreads();
#pragma unroll
  for (int off = 1; off < 256; off <<= 1) {
    int add = (t >= off) ? sdata[t - off] : 0;
    __syncthreads();
    sdata[t] += add;
    __syncthreads();
  }
  if (i < n) tmp[i] = sdata[t];
  if (t == 255) bsum[blockIdx.x] = sdata[255];
}

// step 2: exclusive scan of block sums (nb <= 256) in one block
__global__ __launch_bounds__(256)
void scan2_kernel(const int* __restrict__ bsum, int* __restrict__ boff, int nb) {
  __shared__ int sdata[256];
  int t = threadIdx.x;
  sdata[t] = (t < nb) ? bsum[t] : 0;
  __syncthreads();
#pragma unroll
  for (int off = 1; off < 256; off <<= 1) {
    int add = (t >= off) ? sdata[t - off] : 0;
    __syncthreads();
    sdata[t] += add;
    __syncthreads();
  }
  if (t < nb) boff[t] = (t == 0) ? 0 : sdata[t - 1];
}

// step 3: row_ptr[i+1] = tmp[i] + boff[i/256]; row_ptr[0] = 0
__global__ __launch_bounds__(256)
void scan3_kernel(const int* __restrict__ tmp, const int* __restrict__ boff,
                  int* __restrict__ row_ptr, int n) {
  int i = blockIdx.x * 256 + threadIdx.x;
  if (i == 0) row_ptr[0] = 0;
  if (i < n) row_ptr[i + 1] = tmp[i] + boff[i >> 8];
}

__global__ void scatter_kernel(const int* __restrict__ rows, const int* __restrict__ cols,
                               const float* __restrict__ vals, const int* __restrict__ row_ptr,
                               int* __restrict__ cursor, int* __restrict__ s_col,
                               float* __restrict__ s_val, int e) {
  int i = blockIdx.x * blockDim.x + threadIdx.x;
  if (i < e) {
    int r = rows[i];
    int p = row_ptr[r] + atomicAdd(&cursor[r], 1);
    s_col[p] = cols[i];
    s_val[p] = vals[i];
  }
}

// ---------------------------------------------------------------- SpMM (CSR gather)
// out[r,:] = relu( sum_e val_e * sup[col_e,:] + bias )
// R3: 32 lanes per row, float4 per lane (128 feats), unroll 4 ->
// 4 outstanding 512B row-gathers per row. 256 thr = 8 rows per block.
__global__ __launch_bounds__(256)
void spmm_kernel(const float4* __restrict__ sup, const int* __restrict__ row_ptr,
                 const int* __restrict__ s_col, const float* __restrict__ s_val,
                 const float4* __restrict__ bias, float4* __restrict__ out, int n) {
  const int g = threadIdx.x >> 5;      // row group within block (0..7)
  const int l = threadIdx.x & 31;      // lane within group: feats [4l,4l+4)
  const int r = blockIdx.x * 8 + g;
  if (r >= n) return;
  const int beg = row_ptr[r], end = row_ptr[r + 1];

  float4 acc = make_float4(0.f, 0.f, 0.f, 0.f);
  int i = beg;
  for (; i + 3 < end; i += 4) {
    int c0 = s_col[i], c1 = s_col[i + 1], c2 = s_col[i + 2], c3 = s_col[i + 3];
    float v0 = s_val[i], v1 = s_val[i + 1], v2 = s_val[i + 2], v3 = s_val[i + 3];
    float4 g0 = sup[(size_t)c0 * 32 + l];
    float4 g1 = sup[(size_t)c1 * 32 + l];
    float4 g2 = sup[(size_t)c2 * 32 + l];
    float4 g3 = sup[(size_t)c3 * 32 + l];
    acc.x = fmaf(v0, g0.x, acc.x); acc.y = fmaf(v0, g0.y, acc.y);
    acc.z = fmaf(v0, g0.z, acc.z); acc.w = fmaf(v0, g0.w, acc.w);
    acc.x = fmaf(v1, g1.x, acc.x); acc.y = fmaf(v1, g1.y, acc.y);
    acc.z = fmaf(v1, g1.z, acc.z); acc.w = fmaf(v1, g1.w, acc.w);
    acc.x = fmaf(v2, g2.x, acc.x); acc.y = fmaf(v2, g2.y, acc.y);
    acc.z = fmaf(v2, g2.z, acc.z); acc.w = fmaf(v2, g2.w, acc.w);
    acc.x = fmaf(v3, g3.x, acc.x); acc.y = fmaf(v3, g3.y, acc.y);
    acc.z = fmaf(v3, g3.z, acc.z); acc.w = fmaf(v3, g3.w, acc.w);
  }
  for (; i < end; ++i) {
    int c = s_col[i];
    float v = s_val[i];
    float4 gg = sup[(size_t)c * 32 + l];
    acc.x = fmaf(v, gg.x, acc.x); acc.y = fmaf(v, gg.y, acc.y);
    acc.z = fmaf(v, gg.z, acc.z); acc.w = fmaf(v, gg.w, acc.w);
  }

  float4 b = bias[l];
  acc.x = fmaxf(acc.x + b.x, 0.f);
  acc.y = fmaxf(acc.y + b.y, 0.f);
  acc.z = fmaxf(acc.z + b.z, 0.f);
  acc.w = fmaxf(acc.w + b.w, 0.f);
  out[(size_t)r * 32 + l] = acc;
}

// ---------------------------------------------------------------- launch
extern "C" void kernel_launch(void* const* d_in, const int* in_sizes, int n_in,
                              void* d_out, int out_size, void* d_ws, size_t ws_size,
                              hipStream_t stream) {
  const float* x        = (const float*)d_in[0];
  const int*   edge_row = (const int*)d_in[1];
  const int*   edge_col = (const int*)d_in[2];
  const float* edge_val = (const float*)d_in[3];
  const float* W_gc0 = (const float*)d_in[4];
  const float* b_gc0 = (const float*)d_in[5];
  const float* W_gc1 = (const float*)d_in[6];
  const float* b_gc1 = (const float*)d_in[7];
  const float* Wm1 = (const float*)d_in[8];
  const float* bm1 = (const float*)d_in[9];
  const float* Wm2 = (const float*)d_in[10];
  const float* bm2 = (const float*)d_in[11];
  const float* Wv1 = (const float*)d_in[12];
  const float* bv1 = (const float*)d_in[13];
  const float* Wv2 = (const float*)d_in[14];
  const float* bv2 = (const float*)d_in[15];

  const int N = in_sizes[0] / 128;   // 50000
  const int E = in_sizes[1];         // 800000
  const int NB = (N + 255) / 256;    // scan blocks (196)

  // workspace layout (bytes)
  char* ws = (char*)d_ws;
  float* bufA   = (float*)(ws);                              // N*128 f32
  float* bufB   = (float*)(ws + (size_t)N * 128 * 4);        // N*128 f32
  float* s_val  = (float*)(ws + (size_t)N * 128 * 8);        // E f32
  int*   s_col  = (int*)  (ws + (size_t)N * 128 * 8 + (size_t)E * 4);
  int*   row_ptr= (int*)  (ws + (size_t)N * 128 * 8 + (size_t)E * 8);
  int*   counts = (int*)  ((char*)row_ptr + 200064);         // N ints
  int*   cursor = counts + N;                                // N ints
  int*   tmp    = cursor + N;                                // N ints
  int*   bsum   = tmp + N;                                   // 256 ints
  int*   boff   = bsum + 256;                                // 256 ints
  float* t1     = bufA;                                      // N*64 f32, reuses bufA

  float* out_mean = (float*)d_out;
  float* out_lvar = out_mean + (size_t)N * 64;

  // ---- CSR build (same work every call; ws re-poisoned each launch)
  hipMemsetAsync(counts, 0, (size_t)2 * N * 4, stream);
  hist_kernel<<<(E + 255) / 256, 256, 0, stream>>>(edge_row, counts, E);
  scan1_kernel<<<NB, 256, 0, stream>>>(counts, tmp, bsum, N);
  scan2_kernel<<<1, 256, 0, stream>>>(bsum, boff, NB);
  scan3_kernel<<<NB, 256, 0, stream>>>(tmp, boff, row_ptr, N);
  scatter_kernel<<<(E + 255) / 256, 256, 0, stream>>>(edge_row, edge_col, edge_val,
                                                      row_ptr, cursor, s_col, s_val, E);

  // ---- layer 1: support = x @ W_gc0 ; h1 = relu(agg + b_gc0)
  gemm_kernel<128, 128, false, false><<<(N + 31) / 32, 256, 0, stream>>>(x, W_gc0, nullptr, bufA, N);
  spmm_kernel<<<(N + 7) / 8, 256, 0, stream>>>((const float4*)bufA, row_ptr, s_col, s_val,
                                               (const float4*)b_gc0, (float4*)bufB, N);

  // ---- layer 2
  gemm_kernel<128, 128, false, false><<<(N + 31) / 32, 256, 0, stream>>>(bufB, W_gc1, nullptr, bufA, N);
  spmm_kernel<<<(N + 7) / 8, 256, 0, stream>>>((const float4*)bufA, row_ptr, s_col, s_val,
                                               (const float4*)b_gc1, (float4*)bufB, N);
  // bufB now holds h2

  // ---- mean head
  gemm_kernel<128, 64, true, true><<<(N + 63) / 64, 256, 0, stream>>>(bufB, Wm1, bm1, t1, N);
  gemm_kernel<64, 64, false, true><<<(N + 63) / 64, 256, 0, stream>>>(t1, Wm2, bm2, out_mean, N);

  // ---- logvar head
  gemm_kernel<128, 64, true, true><<<(N + 63) / 64, 256, 0, stream>>>(bufB, Wv1, bv1, t1, N);
  gemm_kernel<64, 64, false, true><<<(N + 63) / 64, 256, 0, stream>>>(t1, Wv2, bv2, out_lvar, N);
}

// Round 4
// 428.989 us; speedup vs baseline: 1.2463x; 1.0186x over previous
//
#include <hip/hip_runtime.h>

// GCNEncoder: h1 = relu(SpMM(x@W0) + b0); h2 = relu(SpMM(h1@W1) + b1)
// mean = relu(h2@Wm1+bm1)@Wm2+bm2 ; logvar = relu(h2@Wv1+bv1)@Wv2+bv2
// All fp32. SpMM via on-device CSR build (no fp32 atomics in hot loop).
// R2: hierarchical scan (90us -> ~5us).
// R3: SpMM float4 gathers, 32 lanes/row, unroll-4 (66 -> <40us).
// R4: scatter writes packed (col,val) as one 8B store (was 2x 4B to two
//     arrays -> 13x write amplification, WRITE_SIZE 82MB for 6.4MB payload);
//     cursor pre-init to row_ptr in scan3 (drops a random load + memset).

// ---------------------------------------------------------------- GEMM
// C[n,M] = A[n,K] @ W[K,M] (+bias, relu). 256 thr, 4x4 register blocking,
// K chunked by 64 so LDS stays <64KB/block.
template<int K, int M, bool RELU, bool BIAS>
__global__ __launch_bounds__(256)
void gemm_kernel(const float* __restrict__ A, const float* __restrict__ W,
                 const float* __restrict__ bias, float* __restrict__ C, int n) {
  constexpr int CG = M / 4;        // col groups (32 for M=128, 16 for M=64)
  constexpr int RG = 256 / CG;     // row groups
  constexpr int ROWS = RG * 4;     // rows per block (32 or 64)
  constexpr int KC = 64;           // K chunk
  constexpr int PAD = (CG == 32) ? 0 : 4;  // pad keeps a-reads <=2-way (free)

  __shared__ float As[ROWS][KC + PAD];
  __shared__ float Ws[KC][M];

  const int t = threadIdx.x;
  const int row0 = blockIdx.x * ROWS;
  const int cg = t % CG, rg = t / CG;
  const int c0 = cg * 4, r0 = rg * 4;

  float acc[4][4] = {};

  for (int kc = 0; kc < K; kc += KC) {
    // stage W chunk [KC x M]
    for (int i = t; i < KC * M / 4; i += 256) {
      int lr = i / (M / 4), lc = (i % (M / 4)) * 4;
      *(float4*)&Ws[lr][lc] = *(const float4*)&W[(size_t)(kc + lr) * M + lc];
    }
    // stage A chunk [ROWS x KC]
    for (int i = t; i < ROWS * KC / 4; i += 256) {
      int lr = i / (KC / 4), lc = (i % (KC / 4)) * 4;
      float4 v = make_float4(0.f, 0.f, 0.f, 0.f);
      int gr = row0 + lr;
      if (gr < n) v = *(const float4*)&A[(size_t)gr * K + kc + lc];
      *(float4*)&As[lr][lc] = v;
    }
    __syncthreads();

#pragma unroll 4
    for (int k4 = 0; k4 < KC; k4 += 4) {
      float4 av[4];
#pragma unroll
      for (int i = 0; i < 4; ++i) av[i] = *(const float4*)&As[r0 + i][k4];
#pragma unroll
      for (int j = 0; j < 4; ++j) {
        float4 b = *(const float4*)&Ws[k4 + j][c0];
#pragma unroll
        for (int i = 0; i < 4; ++i) {
          float a = (j == 0) ? av[i].x : (j == 1) ? av[i].y : (j == 2) ? av[i].z : av[i].w;
          acc[i][0] = fmaf(a, b.x, acc[i][0]);
          acc[i][1] = fmaf(a, b.y, acc[i][1]);
          acc[i][2] = fmaf(a, b.z, acc[i][2]);
          acc[i][3] = fmaf(a, b.w, acc[i][3]);
        }
      }
    }
    __syncthreads();
  }

#pragma unroll
  for (int i = 0; i < 4; ++i) {
    int r = row0 + r0 + i;
    if (r < n) {
      float4 v = make_float4(acc[i][0], acc[i][1], acc[i][2], acc[i][3]);
      if constexpr (BIAS) {
        v.x += bias[c0 + 0]; v.y += bias[c0 + 1];
        v.z += bias[c0 + 2]; v.w += bias[c0 + 3];
      }
      if constexpr (RELU) {
        v.x = fmaxf(v.x, 0.f); v.y = fmaxf(v.y, 0.f);
        v.z = fmaxf(v.z, 0.f); v.w = fmaxf(v.w, 0.f);
      }
      *(float4*)&C[(size_t)r * M + c0] = v;
    }
  }
}

// ---------------------------------------------------------------- CSR build
__global__ void hist_kernel(const int* __restrict__ rows, int* __restrict__ counts, int e) {
  int i = blockIdx.x * blockDim.x + threadIdx.x;
  if (i < e) atomicAdd(&counts[rows[i]], 1);
}

// hierarchical scan, step 1: per-block inclusive scan of counts -> tmp,
// block total -> bsum[block]
__global__ __launch_bounds__(256)
void scan1_kernel(const int* __restrict__ counts, int* __restrict__ tmp,
                  int* __restrict__ bsum, int n) {
  __shared__ int sdata[256];
  int t = threadIdx.x;
  int i = blockIdx.x * 256 + t;
  sdata[t] = (i < n) ? counts[i] : 0;
  __syncthreads();
#pragma unroll
  for (int off = 1; off < 256; off <<= 1) {
    int add = (t >= off) ? sdata[t - off] : 0;
    __syncthreads();
    sdata[t] += add;
    __syncthreads();
  }
  if (i < n) tmp[i] = sdata[t];
  if (t == 255) bsum[blockIdx.x] = sdata[255];
}

// step 2: exclusive scan of block sums (nb <= 256) in one block
__global__ __launch_bounds__(256)
void scan2_kernel(const int* __restrict__ bsum, int* __restrict__ boff, int nb) {
  __shared__ int sdata[256];
  int t = threadIdx.x;
  sdata[t] = (t < nb) ? bsum[t] : 0;
  __syncthreads();
#pragma unroll
  for (int off = 1; off < 256; off <<= 1) {
    int add = (t >= off) ? sdata[t - off] : 0;
    __syncthreads();
    sdata[t] += add;
    __syncthreads();
  }
  if (t < nb) boff[t] = (t == 0) ? 0 : sdata[t - 1];
}

// step 3: row_ptr[i+1] = incl(i); cursor[i] = incl(i) - counts[i] (= row_ptr[i])
__global__ __launch_bounds__(256)
void scan3_kernel(const int* __restrict__ tmp, const int* __restrict__ boff,
                  const int* __restrict__ counts, int* __restrict__ row_ptr,
                  int* __restrict__ cursor, int n) {
  int i = blockIdx.x * 256 + threadIdx.x;
  if (i == 0) row_ptr[0] = 0;
  if (i < n) {
    int incl = tmp[i] + boff[i >> 8];
    row_ptr[i + 1] = incl;
    cursor[i] = incl - counts[i];
  }
}

// scatter packed (col, val_bits) as one 8B store; cursor pre-init'd to row_ptr
__global__ void scatter_kernel(const int* __restrict__ rows, const int* __restrict__ cols,
                               const float* __restrict__ vals,
                               int* __restrict__ cursor, int2* __restrict__ s_pack, int e) {
  int i = blockIdx.x * blockDim.x + threadIdx.x;
  if (i < e) {
    int r = rows[i];
    int p = atomicAdd(&cursor[r], 1);
    s_pack[p] = make_int2(cols[i], __float_as_int(vals[i]));
  }
}

// ---------------------------------------------------------------- SpMM (CSR gather)
// out[r,:] = relu( sum_e val_e * sup[col_e,:] + bias )
// 32 lanes per row, float4 per lane (128 feats), unroll 4 ->
// 4 outstanding 512B row-gathers per row. 256 thr = 8 rows per block.
__global__ __launch_bounds__(256)
void spmm_kernel(const float4* __restrict__ sup, const int* __restrict__ row_ptr,
                 const int2* __restrict__ s_pack,
                 const float4* __restrict__ bias, float4* __restrict__ out, int n) {
  const int g = threadIdx.x >> 5;      // row group within block (0..7)
  const int l = threadIdx.x & 31;      // lane within group: feats [4l,4l+4)
  const int r = blockIdx.x * 8 + g;
  if (r >= n) return;
  const int beg = row_ptr[r], end = row_ptr[r + 1];

  float4 acc = make_float4(0.f, 0.f, 0.f, 0.f);
  int i = beg;
  for (; i + 3 < end; i += 4) {
    int2 e0 = s_pack[i], e1 = s_pack[i + 1], e2 = s_pack[i + 2], e3 = s_pack[i + 3];
    float4 g0 = sup[(size_t)e0.x * 32 + l];
    float4 g1 = sup[(size_t)e1.x * 32 + l];
    float4 g2 = sup[(size_t)e2.x * 32 + l];
    float4 g3 = sup[(size_t)e3.x * 32 + l];
    float v0 = __int_as_float(e0.y), v1 = __int_as_float(e1.y);
    float v2 = __int_as_float(e2.y), v3 = __int_as_float(e3.y);
    acc.x = fmaf(v0, g0.x, acc.x); acc.y = fmaf(v0, g0.y, acc.y);
    acc.z = fmaf(v0, g0.z, acc.z); acc.w = fmaf(v0, g0.w, acc.w);
    acc.x = fmaf(v1, g1.x, acc.x); acc.y = fmaf(v1, g1.y, acc.y);
    acc.z = fmaf(v1, g1.z, acc.z); acc.w = fmaf(v1, g1.w, acc.w);
    acc.x = fmaf(v2, g2.x, acc.x); acc.y = fmaf(v2, g2.y, acc.y);
    acc.z = fmaf(v2, g2.z, acc.z); acc.w = fmaf(v2, g2.w, acc.w);
    acc.x = fmaf(v3, g3.x, acc.x); acc.y = fmaf(v3, g3.y, acc.y);
    acc.z = fmaf(v3, g3.z, acc.z); acc.w = fmaf(v3, g3.w, acc.w);
  }
  for (; i < end; ++i) {
    int2 e0 = s_pack[i];
    float v = __int_as_float(e0.y);
    float4 gg = sup[(size_t)e0.x * 32 + l];
    acc.x = fmaf(v, gg.x, acc.x); acc.y = fmaf(v, gg.y, acc.y);
    acc.z = fmaf(v, gg.z, acc.z); acc.w = fmaf(v, gg.w, acc.w);
  }

  float4 b = bias[l];
  acc.x = fmaxf(acc.x + b.x, 0.f);
  acc.y = fmaxf(acc.y + b.y, 0.f);
  acc.z = fmaxf(acc.z + b.z, 0.f);
  acc.w = fmaxf(acc.w + b.w, 0.f);
  out[(size_t)r * 32 + l] = acc;
}

// ---------------------------------------------------------------- launch
extern "C" void kernel_launch(void* const* d_in, const int* in_sizes, int n_in,
                              void* d_out, int out_size, void* d_ws, size_t ws_size,
                              hipStream_t stream) {
  const float* x        = (const float*)d_in[0];
  const int*   edge_row = (const int*)d_in[1];
  const int*   edge_col = (const int*)d_in[2];
  const float* edge_val = (const float*)d_in[3];
  const float* W_gc0 = (const float*)d_in[4];
  const float* b_gc0 = (const float*)d_in[5];
  const float* W_gc1 = (const float*)d_in[6];
  const float* b_gc1 = (const float*)d_in[7];
  const float* Wm1 = (const float*)d_in[8];
  const float* bm1 = (const float*)d_in[9];
  const float* Wm2 = (const float*)d_in[10];
  const float* bm2 = (const float*)d_in[11];
  const float* Wv1 = (const float*)d_in[12];
  const float* bv1 = (const float*)d_in[13];
  const float* Wv2 = (const float*)d_in[14];
  const float* bv2 = (const float*)d_in[15];

  const int N = in_sizes[0] / 128;   // 50000
  const int E = in_sizes[1];         // 800000
  const int NB = (N + 255) / 256;    // scan blocks (196)

  // workspace layout (bytes)
  char* ws = (char*)d_ws;
  float* bufA   = (float*)(ws);                              // N*128 f32
  float* bufB   = (float*)(ws + (size_t)N * 128 * 4);        // N*128 f32
  int2*  s_pack = (int2*) (ws + (size_t)N * 128 * 8);        // E x 8B
  int*   row_ptr= (int*)  (ws + (size_t)N * 128 * 8 + (size_t)E * 8);
  int*   counts = (int*)  ((char*)row_ptr + 200064);         // N ints
  int*   cursor = counts + N;                                // N ints
  int*   tmp    = cursor + N;                                // N ints
  int*   bsum   = tmp + N;                                   // 256 ints
  int*   boff   = bsum + 256;                                // 256 ints
  float* t1     = bufA;                                      // N*64 f32, reuses bufA

  float* out_mean = (float*)d_out;
  float* out_lvar = out_mean + (size_t)N * 64;

  // ---- CSR build (same work every call; ws re-poisoned each launch)
  hipMemsetAsync(counts, 0, (size_t)N * 4, stream);
  hist_kernel<<<(E + 255) / 256, 256, 0, stream>>>(edge_row, counts, E);
  scan1_kernel<<<NB, 256, 0, stream>>>(counts, tmp, bsum, N);
  scan2_kernel<<<1, 256, 0, stream>>>(bsum, boff, NB);
  scan3_kernel<<<NB, 256, 0, stream>>>(tmp, boff, counts, row_ptr, cursor, N);
  scatter_kernel<<<(E + 255) / 256, 256, 0, stream>>>(edge_row, edge_col, edge_val,
                                                      cursor, s_pack, E);

  // ---- layer 1: support = x @ W_gc0 ; h1 = relu(agg + b_gc0)
  gemm_kernel<128, 128, false, false><<<(N + 31) / 32, 256, 0, stream>>>(x, W_gc0, nullptr, bufA, N);
  spmm_kernel<<<(N + 7) / 8, 256, 0, stream>>>((const float4*)bufA, row_ptr, s_pack,
                                               (const float4*)b_gc0, (float4*)bufB, N);

  // ---- layer 2
  gemm_kernel<128, 128, false, false><<<(N + 31) / 32, 256, 0, stream>>>(bufB, W_gc1, nullptr, bufA, N);
  spmm_kernel<<<(N + 7) / 8, 256, 0, stream>>>((const float4*)bufA, row_ptr, s_pack,
                                               (const float4*)b_gc1, (float4*)bufB, N);
  // bufB now holds h2

  // ---- mean head
  gemm_kernel<128, 64, true, true><<<(N + 63) / 64, 256, 0, stream>>>(bufB, Wm1, bm1, t1, N);
  gemm_kernel<64, 64, false, true><<<(N + 63) / 64, 256, 0, stream>>>(t1, Wm2, bm2, out_mean, N);

  // ---- logvar head
  gemm_kernel<128, 64, true, true><<<(N + 63) / 64, 256, 0, stream>>>(bufB, Wv1, bv1, t1, N);
  gemm_kernel<64, 64, false, true><<<(N + 63) / 64, 256, 0, stream>>>(t1, Wv2, bv2, out_lvar, N);
}

// Round 5
// 319.325 us; speedup vs baseline: 1.6743x; 1.3434x over previous
//
#include <hip/hip_runtime.h>

// GCNEncoder: h1 = relu(SpMM(x@W0) + b0); h2 = relu(SpMM(h1@W1) + b1)
// mean = relu(h2@Wm1+bm1)@Wm2+bm2 ; logvar = relu(h2@Wv1+bv1)@Wv2+bv2
// R2: hierarchical scan (90us -> ~5us).
// R3: SpMM float4 gathers, 32 lanes/row, unroll-4.
// R4: scatter packs (col,val) in one 8B store (13x write amp fix).
// R5: f16 pipeline. All GEMMs via mfma_f32_16x16x32_f16 (fp32 accum);
//     weights pre-swizzled to fragment order (L2-resident, coalesced B-loads);
//     SpMM gathers f16 rows (256B vs 512B -> halves the 8-XCD fill floor).

typedef _Float16 half8 __attribute__((ext_vector_type(8)));
typedef _Float16 half4 __attribute__((ext_vector_type(4)));
typedef float floatx4 __attribute__((ext_vector_type(4)));

// ---------------------------------------------------------------- f16 GEMM
// C[n,M] = A[n,K]@W[K,M] (+bias,relu). A: f16 row-major. Wswz: f16 fragment
// order [(ks*NT+nt)*64 + lane]*8 + j  with k=ks*32+quad*8+j, n=nt*16+(lane&15).
// Block: 256 thr = 4 waves, 64 rows/block, each wave 16 rows x M cols.
// A-frag (verified m89/m120): lane holds A[m=lane&15][k=quad*8+j].
// C/D (verified m89): col=lane&15, row=quad*4+reg.
template<int K, int M, bool RELU, bool BIAS, typename OutT>
__global__ __launch_bounds__(256)
void gemm16(const _Float16* __restrict__ A, const _Float16* __restrict__ Wswz,
            const float* __restrict__ bias, OutT* __restrict__ C, int n) {
  constexpr int NT = M / 16, KS = K / 32;
  const int lane = threadIdx.x & 63;
  const int wave = threadIdx.x >> 6;
  const int quad = lane >> 4, l16 = lane & 15;
  const int r_base = blockIdx.x * 64 + wave * 16;

  int arow = r_base + l16;
  if (arow >= n) arow = n - 1;          // clamp; clamped rows never stored
  const _Float16* Ap = A + (size_t)arow * K + quad * 8;

  floatx4 acc[NT] = {};

#pragma unroll
  for (int ks = 0; ks < KS; ++ks) {
    half8 a = *(const half8*)(Ap + ks * 32);
#pragma unroll
    for (int nt = 0; nt < NT; ++nt) {
      half8 b = *(const half8*)(Wswz + ((size_t)(ks * NT + nt) * 64 + lane) * 8);
      acc[nt] = __builtin_amdgcn_mfma_f32_16x16x32_f16(a, b, acc[nt], 0, 0, 0);
    }
  }

#pragma unroll
  for (int nt = 0; nt < NT; ++nt) {
    const int col = nt * 16 + l16;
    float bv = BIAS ? bias[col] : 0.f;
#pragma unroll
    for (int r = 0; r < 4; ++r) {
      int row = r_base + quad * 4 + r;
      if (row < n) {
        float v = acc[nt][r] + bv;
        if constexpr (RELU) v = fmaxf(v, 0.f);
        C[(size_t)row * M + col] = (OutT)v;
      }
    }
  }
}

// ---------------------------------------------------------------- conversions
// x fp32 -> f16, vectorized
__global__ __launch_bounds__(256)
void f32_to_f16_kernel(const float4* __restrict__ in, half4* __restrict__ out, int n4) {
  int stride = gridDim.x * 256;
  for (int i = blockIdx.x * 256 + threadIdx.x; i < n4; i += stride) {
    float4 v = in[i];
    half4 h = { (_Float16)v.x, (_Float16)v.y, (_Float16)v.z, (_Float16)v.w };
    out[i] = h;
  }
}

// all six weights fp32 row-major -> f16 fragment-swizzled, one dispatch
__global__ __launch_bounds__(256)
void wconv_kernel(const float* __restrict__ w0, const float* __restrict__ w1,
                  const float* __restrict__ wm1, const float* __restrict__ wv1,
                  const float* __restrict__ wm2, const float* __restrict__ wv2,
                  _Float16* __restrict__ d0, _Float16* __restrict__ d1,
                  _Float16* __restrict__ dm1, _Float16* __restrict__ dv1,
                  _Float16* __restrict__ dm2, _Float16* __restrict__ dv2) {
  int i = blockIdx.x * 256 + threadIdx.x;
  const float* src; _Float16* dst; int K, M, li;
  if      (i < 16384) { src = w0;  dst = d0;  K = 128; M = 128; li = i; }
  else if (i < 32768) { src = w1;  dst = d1;  K = 128; M = 128; li = i - 16384; }
  else if (i < 40960) { src = wm1; dst = dm1; K = 128; M = 64;  li = i - 32768; }
  else if (i < 49152) { src = wv1; dst = dv1; K = 128; M = 64;  li = i - 40960; }
  else if (i < 53248) { src = wm2; dst = dm2; K = 64;  M = 64;  li = i - 49152; }
  else if (i < 57344) { src = wv2; dst = dv2; K = 64;  M = 64;  li = i - 53248; }
  else return;
  int NT = M / 16;
  int j = li & 7, lane = (li >> 3) & 63, t = li >> 9;
  int nt = t % NT, ks = t / NT;
  int k = ks * 32 + (lane >> 4) * 8 + j;
  int nn = nt * 16 + (lane & 15);
  dst[li] = (_Float16)src[k * M + nn];
}

// ---------------------------------------------------------------- CSR build
__global__ void hist_kernel(const int* __restrict__ rows, int* __restrict__ counts, int e) {
  int i = blockIdx.x * blockDim.x + threadIdx.x;
  if (i < e) atomicAdd(&counts[rows[i]], 1);
}

__global__ __launch_bounds__(256)
void scan1_kernel(const int* __restrict__ counts, int* __restrict__ tmp,
                  int* __restrict__ bsum, int n) {
  __shared__ int sdata[256];
  int t = threadIdx.x;
  int i = blockIdx.x * 256 + t;
  sdata[t] = (i < n) ? counts[i] : 0;
  __syncthreads();
#pragma unroll
  for (int off = 1; off < 256; off <<= 1) {
    int add = (t >= off) ? sdata[t - off] : 0;
    __syncthreads();
    sdata[t] += add;
    __syncthreads();
  }
  if (i < n) tmp[i] = sdata[t];
  if (t == 255) bsum[blockIdx.x] = sdata[255];
}

__global__ __launch_bounds__(256)
void scan2_kernel(const int* __restrict__ bsum, int* __restrict__ boff, int nb) {
  __shared__ int sdata[256];
  int t = threadIdx.x;
  sdata[t] = (t < nb) ? bsum[t] : 0;
  __syncthreads();
#pragma unroll
  for (int off = 1; off < 256; off <<= 1) {
    int add = (t >= off) ? sdata[t - off] : 0;
    __syncthreads();
    sdata[t] += add;
    __syncthreads();
  }
  if (t < nb) boff[t] = (t == 0) ? 0 : sdata[t - 1];
}

__global__ __launch_bounds__(256)
void scan3_kernel(const int* __restrict__ tmp, const int* __restrict__ boff,
                  const int* __restrict__ counts, int* __restrict__ row_ptr,
                  int* __restrict__ cursor, int n) {
  int i = blockIdx.x * 256 + threadIdx.x;
  if (i == 0) row_ptr[0] = 0;
  if (i < n) {
    int incl = tmp[i] + boff[i >> 8];
    row_ptr[i + 1] = incl;
    cursor[i] = incl - counts[i];
  }
}

__global__ void scatter_kernel(const int* __restrict__ rows, const int* __restrict__ cols,
                               const float* __restrict__ vals,
                               int* __restrict__ cursor, int2* __restrict__ s_pack, int e) {
  int i = blockIdx.x * blockDim.x + threadIdx.x;
  if (i < e) {
    int r = rows[i];
    int p = atomicAdd(&cursor[r], 1);
    s_pack[p] = make_int2(cols[i], __float_as_int(vals[i]));
  }
}

// ---------------------------------------------------------------- SpMM (f16 gather)
// out[r,:] = relu( sum_e val_e * sup[col_e,:] + bias ), sup/out f16 rows (256B).
// 32 lanes/row, half4 per lane, unroll 4. 256 thr = 8 rows/block.
__global__ __launch_bounds__(256)
void spmm16(const half4* __restrict__ sup, const int* __restrict__ row_ptr,
            const int2* __restrict__ s_pack,
            const float4* __restrict__ bias, half4* __restrict__ out, int n) {
  const int g = threadIdx.x >> 5;
  const int l = threadIdx.x & 31;      // feats [4l, 4l+4)
  const int r = blockIdx.x * 8 + g;
  if (r >= n) return;
  const int beg = row_ptr[r], end = row_ptr[r + 1];

  float4 acc = make_float4(0.f, 0.f, 0.f, 0.f);
  int i = beg;
  for (; i + 3 < end; i += 4) {
    int2 e0 = s_pack[i], e1 = s_pack[i + 1], e2 = s_pack[i + 2], e3 = s_pack[i + 3];
    half4 g0 = sup[(size_t)e0.x * 32 + l];
    half4 g1 = sup[(size_t)e1.x * 32 + l];
    half4 g2 = sup[(size_t)e2.x * 32 + l];
    half4 g3 = sup[(size_t)e3.x * 32 + l];
    float v0 = __int_as_float(e0.y), v1 = __int_as_float(e1.y);
    float v2 = __int_as_float(e2.y), v3 = __int_as_float(e3.y);
    acc.x = fmaf(v0, (float)g0.x, acc.x); acc.y = fmaf(v0, (float)g0.y, acc.y);
    acc.z = fmaf(v0, (float)g0.z, acc.z); acc.w = fmaf(v0, (float)g0.w, acc.w);
    acc.x = fmaf(v1, (float)g1.x, acc.x); acc.y = fmaf(v1, (float)g1.y, acc.y);
    acc.z = fmaf(v1, (float)g1.z, acc.z); acc.w = fmaf(v1, (float)g1.w, acc.w);
    acc.x = fmaf(v2, (float)g2.x, acc.x); acc.y = fmaf(v2, (float)g2.y, acc.y);
    acc.z = fmaf(v2, (float)g2.z, acc.z); acc.w = fmaf(v2, (float)g2.w, acc.w);
    acc.x = fmaf(v3, (float)g3.x, acc.x); acc.y = fmaf(v3, (float)g3.y, acc.y);
    acc.z = fmaf(v3, (float)g3.z, acc.z); acc.w = fmaf(v3, (float)g3.w, acc.w);
  }
  for (; i < end; ++i) {
    int2 e0 = s_pack[i];
    float v = __int_as_float(e0.y);
    half4 gg = sup[(size_t)e0.x * 32 + l];
    acc.x = fmaf(v, (float)gg.x, acc.x); acc.y = fmaf(v, (float)gg.y, acc.y);
    acc.z = fmaf(v, (float)gg.z, acc.z); acc.w = fmaf(v, (float)gg.w, acc.w);
  }

  float4 b = bias[l];
  half4 o = { (_Float16)fmaxf(acc.x + b.x, 0.f),
              (_Float16)fmaxf(acc.y + b.y, 0.f),
              (_Float16)fmaxf(acc.z + b.z, 0.f),
              (_Float16)fmaxf(acc.w + b.w, 0.f) };
  out[(size_t)r * 32 + l] = o;
}

// ---------------------------------------------------------------- launch
extern "C" void kernel_launch(void* const* d_in, const int* in_sizes, int n_in,
                              void* d_out, int out_size, void* d_ws, size_t ws_size,
                              hipStream_t stream) {
  const float* x        = (const float*)d_in[0];
  const int*   edge_row = (const int*)d_in[1];
  const int*   edge_col = (const int*)d_in[2];
  const float* edge_val = (const float*)d_in[3];
  const float* W_gc0 = (const float*)d_in[4];
  const float* b_gc0 = (const float*)d_in[5];
  const float* W_gc1 = (const float*)d_in[6];
  const float* b_gc1 = (const float*)d_in[7];
  const float* Wm1 = (const float*)d_in[8];
  const float* bm1 = (const float*)d_in[9];
  const float* Wm2 = (const float*)d_in[10];
  const float* bm2 = (const float*)d_in[11];
  const float* Wv1 = (const float*)d_in[12];
  const float* bv1 = (const float*)d_in[13];
  const float* Wv2 = (const float*)d_in[14];
  const float* bv2 = (const float*)d_in[15];

  const int N = in_sizes[0] / 128;   // 50000
  const int E = in_sizes[1];         // 800000
  const int NB = (N + 255) / 256;

  // workspace layout
  char* ws = (char*)d_ws;
  _Float16* x16    = (_Float16*)(ws);                            // N*128 f16 (reused as t1)
  _Float16* bufA16 = (_Float16*)(ws + (size_t)N * 256);          // N*128 f16 (support)
  _Float16* bufB16 = (_Float16*)(ws + (size_t)N * 512);          // N*128 f16 (h1/h2)
  int2*  s_pack = (int2*)(ws + (size_t)N * 768);                 // E*8
  char*  p = ws + (size_t)N * 768 + (size_t)E * 8;
  int*   row_ptr = (int*)p;           p += 200064;
  int*   counts  = (int*)p;           p += (size_t)N * 4;
  int*   cursor  = (int*)p;           p += (size_t)N * 4;
  int*   tmp     = (int*)p;           p += (size_t)N * 4;
  int*   bsum    = (int*)p;           p += 1024;
  int*   boff    = (int*)p;           p += 1024;
  _Float16* W0s  = (_Float16*)p;      p += 32768;
  _Float16* W1s  = (_Float16*)p;      p += 32768;
  _Float16* Wm1s = (_Float16*)p;      p += 16384;
  _Float16* Wv1s = (_Float16*)p;      p += 16384;
  _Float16* Wm2s = (_Float16*)p;      p += 8192;
  _Float16* Wv2s = (_Float16*)p;      p += 8192;
  _Float16* t16  = x16;               // head hidden, reuses x16

  float* out_mean = (float*)d_out;
  float* out_lvar = out_mean + (size_t)N * 64;

  // ---- CSR build + conversions
  hipMemsetAsync(counts, 0, (size_t)N * 4, stream);
  hist_kernel<<<(E + 255) / 256, 256, 0, stream>>>(edge_row, counts, E);
  scan1_kernel<<<NB, 256, 0, stream>>>(counts, tmp, bsum, N);
  scan2_kernel<<<1, 256, 0, stream>>>(bsum, boff, NB);
  scan3_kernel<<<NB, 256, 0, stream>>>(tmp, boff, counts, row_ptr, cursor, N);
  scatter_kernel<<<(E + 255) / 256, 256, 0, stream>>>(edge_row, edge_col, edge_val,
                                                      cursor, s_pack, E);
  f32_to_f16_kernel<<<512, 256, 0, stream>>>((const float4*)x, (half4*)x16, N * 32);
  wconv_kernel<<<224, 256, 0, stream>>>(W_gc0, W_gc1, Wm1, Wv1, Wm2, Wv2,
                                        W0s, W1s, Wm1s, Wv1s, Wm2s, Wv2s);

  const int GB = (N + 63) / 64;  // gemm blocks (782)

  // ---- layer 1
  gemm16<128, 128, false, false, _Float16><<<GB, 256, 0, stream>>>(x16, W0s, nullptr, bufA16, N);
  spmm16<<<(N + 7) / 8, 256, 0, stream>>>((const half4*)bufA16, row_ptr, s_pack,
                                          (const float4*)b_gc0, (half4*)bufB16, N);
  // ---- layer 2
  gemm16<128, 128, false, false, _Float16><<<GB, 256, 0, stream>>>(bufB16, W1s, nullptr, bufA16, N);
  spmm16<<<(N + 7) / 8, 256, 0, stream>>>((const half4*)bufA16, row_ptr, s_pack,
                                          (const float4*)b_gc1, (half4*)bufB16, N);
  // bufB16 = h2

  // ---- mean head
  gemm16<128, 64, true, true, _Float16><<<GB, 256, 0, stream>>>(bufB16, Wm1s, bm1, t16, N);
  gemm16<64, 64, false, true, float><<<GB, 256, 0, stream>>>(t16, Wm2s, bm2, out_mean, N);

  // ---- logvar head
  gemm16<128, 64, true, true, _Float16><<<GB, 256, 0, stream>>>(bufB16, Wv1s, bv1, t16, N);
  gemm16<64, 64, false, true, float><<<GB, 256, 0, stream>>>(t16, Wv2s, bv2, out_lvar, N);
}